// Round 1
// baseline (1862.744 us; speedup 1.0000x reference)
//
#include <hip/hip_runtime.h>

static constexpr int N = 100000;
static constexpr int HID = 128;

// ---- Edge pass 1: degree + 4-dim feature aggregation (atomics) ----
__global__ void k_edge_agg4(const int* __restrict__ src, const int* __restrict__ dst,
                            const float* __restrict__ feats,
                            float* __restrict__ deg, float* __restrict__ agg4, int E) {
  int e = blockIdx.x * 256 + threadIdx.x;
  if (e >= E) return;
  int s = src[e], d = dst[e];
  float4 f = *reinterpret_cast<const float4*>(feats + 4 * s);
  atomicAdd(&deg[d], 1.0f);
  float* a = agg4 + 4 * d;
  atomicAdd(a + 0, f.x);
  atomicAdd(a + 1, f.y);
  atomicAdd(a + 2, f.z);
  atomicAdd(a + 3, f.w);
}

// ---- Layer 1: h1 = relu(feats@Ws1 + mean4@Wn1 + b1), one thread per (v,j) ----
__global__ void k_layer1(const float* __restrict__ feats, const float* __restrict__ deg,
                         const float* __restrict__ agg4, const float* __restrict__ ws1,
                         const float* __restrict__ wn1, const float* __restrict__ b1,
                         float* __restrict__ h1) {
  int id = blockIdx.x * 256 + threadIdx.x;
  if (id >= N * HID) return;
  int v = id >> 7, j = id & 127;
  float4 f = *reinterpret_cast<const float4*>(feats + 4 * v);
  float4 a = *reinterpret_cast<const float4*>(agg4 + 4 * v);
  float inv = 1.0f / fmaxf(deg[v], 1.0f);
  float acc = b1[j];
  acc += f.x * ws1[j] + f.y * ws1[HID + j] + f.z * ws1[2 * HID + j] + f.w * ws1[3 * HID + j];
  float accn = a.x * wn1[j] + a.y * wn1[HID + j] + a.z * wn1[2 * HID + j] + a.w * wn1[3 * HID + j];
  acc += inv * accn;
  h1[id] = fmaxf(acc, 0.0f);
}

// ---- Edge pass 2: 128-dim aggregation of h1. One wave per edge, float2/lane. ----
__global__ void k_edge_agg128(const int* __restrict__ src, const int* __restrict__ dst,
                              const float* __restrict__ h1, float* __restrict__ agg,
                              int E) {
  unsigned id = blockIdx.x * 256u + threadIdx.x;
  int e = (int)(id >> 6);
  if (e >= E) return;
  int l = (int)(id & 63u);
  int s = src[e], d = dst[e];
  float2 v = *reinterpret_cast<const float2*>(h1 + s * HID + 2 * l);
  float* a = agg + d * HID + 2 * l;
  atomicAdd(a + 0, v.x);
  atomicAdd(a + 1, v.y);
}

// ---- Layer 2 + output head, fused. 64-node tile per block, 256 threads. ----
// Thread tile: 8 nodes x 4 cols; 64 fp32 FMA per k-step per thread.
__global__ __launch_bounds__(256, 2) void k_layer2_out(
    const float* __restrict__ h1, const float* __restrict__ deg,
    const float* __restrict__ agg, const float* __restrict__ ws2,
    const float* __restrict__ wn2, const float* __restrict__ b2,
    const float* __restrict__ wout, const float* __restrict__ bout,
    float* __restrict__ out) {
  __shared__ float Ah[64 * 132];  // h1 tile [v][k], stride 132 (16B-aligned, pad vs conflicts)
  __shared__ float Am[64 * 132];  // mean tile [v][k]
  const int t = threadIdx.x;
  const int vbase = blockIdx.x * 64;

  // Stage: 2048 float4 per matrix, 8 per thread. agg scaled by 1/max(deg,1) on the fly.
#pragma unroll
  for (int i = 0; i < 8; ++i) {
    int f = t + 256 * i;   // 0..2047
    int v = f >> 5;        // 0..63
    int k4 = f & 31;       // float4 index along k
    int vg = vbase + v;
    float4 hv = make_float4(0.f, 0.f, 0.f, 0.f);
    float4 av = hv;
    float inv = 0.f;
    if (vg < N) {
      hv = *reinterpret_cast<const float4*>(h1 + vg * 128 + 4 * k4);
      av = *reinterpret_cast<const float4*>(agg + vg * 128 + 4 * k4);
      inv = 1.0f / fmaxf(deg[vg], 1.0f);
    }
    *reinterpret_cast<float4*>(&Ah[v * 132 + 4 * k4]) = hv;
    av.x *= inv; av.y *= inv; av.z *= inv; av.w *= inv;
    *reinterpret_cast<float4*>(&Am[v * 132 + 4 * k4]) = av;
  }
  __syncthreads();

  const int r = t >> 5;  // 0..7 -> nodes 8r..8r+7
  const int c = t & 31;  // cols 4c..4c+3
  float acc[8][4];
#pragma unroll
  for (int i = 0; i < 8; ++i)
#pragma unroll
    for (int jj = 0; jj < 4; ++jj) acc[i][jj] = 0.f;

#pragma unroll 2
  for (int k = 0; k < 128; ++k) {
    float as[8], am[8];
#pragma unroll
    for (int i = 0; i < 8; ++i) {
      as[i] = Ah[(8 * r + i) * 132 + k];  // same addr across 32 lanes -> broadcast
      am[i] = Am[(8 * r + i) * 132 + k];
    }
    float4 wsv = *reinterpret_cast<const float4*>(ws2 + k * 128 + 4 * c);
    float4 wnv = *reinterpret_cast<const float4*>(wn2 + k * 128 + 4 * c);
    float wsa[4] = {wsv.x, wsv.y, wsv.z, wsv.w};
    float wna[4] = {wnv.x, wnv.y, wnv.z, wnv.w};
#pragma unroll
    for (int i = 0; i < 8; ++i)
#pragma unroll
      for (int jj = 0; jj < 4; ++jj)
        acc[i][jj] += as[i] * wsa[jj] + am[i] * wna[jj];
  }
  __syncthreads();

  // h2 tile (relu(acc + b2)) into LDS (reuse Ah), then 128->2 output dot.
#pragma unroll
  for (int i = 0; i < 8; ++i) {
    int v = 8 * r + i;
#pragma unroll
    for (int jj = 0; jj < 4; ++jj) {
      int j = 4 * c + jj;
      Ah[v * 132 + j] = fmaxf(acc[i][jj] + b2[j], 0.f);
    }
  }
  __syncthreads();

  if (t < 128) {
    int v = t >> 1, cls = t & 1;
    int vg = vbase + v;
    if (vg < N) {
      float sacc = bout[cls];
#pragma unroll 8
      for (int j = 0; j < 128; ++j) sacc += Ah[v * 132 + j] * wout[2 * j + cls];
      out[2 * vg + cls] = sacc;
    }
  }
}

extern "C" void kernel_launch(void* const* d_in, const int* in_sizes, int n_in,
                              void* d_out, int out_size, void* d_ws, size_t ws_size,
                              hipStream_t stream) {
  const float* feats = (const float*)d_in[0];
  const int* src = (const int*)d_in[1];
  const int* dst = (const int*)d_in[2];
  const float* ws1 = (const float*)d_in[3];
  const float* wn1 = (const float*)d_in[4];
  const float* b1 = (const float*)d_in[5];
  const float* ws2 = (const float*)d_in[6];
  const float* wn2 = (const float*)d_in[7];
  const float* b2 = (const float*)d_in[8];
  const float* wout = (const float*)d_in[9];
  const float* bout = (const float*)d_in[10];
  float* out = (float*)d_out;
  const int E = in_sizes[1];

  float* wsf = (float*)d_ws;
  float* deg = wsf;               // N floats
  float* agg4 = wsf + N;          // 4N
  float* agg = wsf + 5 * N;       // 128N
  float* h1 = wsf + 133 * N;      // 128N   (total 261N floats = 104.4 MB)

  // Zero the atomic-accumulated regions (deg + agg4 + agg128).
  hipMemsetAsync(d_ws, 0, (size_t)133 * N * sizeof(float), stream);

  k_edge_agg4<<<(E + 255) / 256, 256, 0, stream>>>(src, dst, feats, deg, agg4, E);
  k_layer1<<<(N * HID) / 256, 256, 0, stream>>>(feats, deg, agg4, ws1, wn1, b1, h1);
  k_edge_agg128<<<(E * 64 + 255) / 256, 256, 0, stream>>>(src, dst, h1, agg, E);
  k_layer2_out<<<(N + 63) / 64, 256, 0, stream>>>(h1, deg, agg, ws2, wn2, b2, wout, bout, out);
}

// Round 2
// 527.897 us; speedup vs baseline: 3.5286x; 3.5286x over previous
//
#include <hip/hip_runtime.h>
#include <hip/hip_bf16.h>

static constexpr int N = 100000;
static constexpr int HID = 128;
static constexpr int NB = (N + 255) / 256;  // 391 scan blocks

// ---------- bf16 helpers (RNE) ----------
static __device__ __forceinline__ unsigned short f2bf(float x) {
  unsigned u = __float_as_uint(x);
  return (unsigned short)((u + 0x7fffu + ((u >> 16) & 1u)) >> 16);
}
static __device__ __forceinline__ float bf2f(unsigned short u) {
  return __uint_as_float(((unsigned)u) << 16);
}

// ---------- CSR build ----------
__global__ void k_count(const int* __restrict__ dst, unsigned* __restrict__ cnt, int E) {
  int e = blockIdx.x * 256 + threadIdx.x;
  if (e < E) atomicAdd(&cnt[dst[e]], 1u);
}

__global__ void k_blocksum(const unsigned* __restrict__ cnt, unsigned* __restrict__ bs) {
  __shared__ unsigned s[256];
  int i = blockIdx.x * 256 + threadIdx.x;
  s[threadIdx.x] = (i < N) ? cnt[i] : 0u;
  __syncthreads();
  for (int off = 128; off > 0; off >>= 1) {
    if (threadIdx.x < off) s[threadIdx.x] += s[threadIdx.x + off];
    __syncthreads();
  }
  if (threadIdx.x == 0) bs[blockIdx.x] = s[0];
}

__global__ void k_scanbs(const unsigned* __restrict__ bs, unsigned* __restrict__ bsoff) {
  __shared__ unsigned s[512];
  int t = threadIdx.x;
  unsigned v = (t < NB) ? bs[t] : 0u;
  s[t] = v;
  __syncthreads();
  for (int off = 1; off < 512; off <<= 1) {
    unsigned x = (t >= off) ? s[t - off] : 0u;
    __syncthreads();
    s[t] += x;
    __syncthreads();
  }
  if (t < NB) bsoff[t] = s[t] - v;  // exclusive
}

__global__ void k_scatter_off(const unsigned* __restrict__ cnt, const unsigned* __restrict__ bsoff,
                              unsigned* __restrict__ roff) {
  __shared__ unsigned s[256];
  int t = threadIdx.x;
  int i = blockIdx.x * 256 + t;
  unsigned v = (i < N) ? cnt[i] : 0u;
  s[t] = v;
  __syncthreads();
  for (int off = 1; off < 256; off <<= 1) {
    unsigned x = (t >= off) ? s[t - off] : 0u;
    __syncthreads();
    s[t] += x;
    __syncthreads();
  }
  if (i < N) roff[i] = bsoff[blockIdx.x] + s[t] - v;  // exclusive prefix
}

// After this, roff[v] becomes the INCLUSIVE end of row v; start = roff[v]-cnt[v].
__global__ void k_fill(const int* __restrict__ src, const int* __restrict__ dst,
                       unsigned* __restrict__ roff, int* __restrict__ csr, int E) {
  int e = blockIdx.x * 256 + threadIdx.x;
  if (e >= E) return;
  unsigned pos = atomicAdd(&roff[dst[e]], 1u);
  csr[pos] = src[e];
}

// ---------- Layer 1 fused: gather feats + mean + dense(4->128) + relu -> h1 (bf16) ----------
__global__ void k_layer1(const float* __restrict__ feats, const unsigned* __restrict__ cnt,
                         const unsigned* __restrict__ roff, const int* __restrict__ csr,
                         const float* __restrict__ ws1, const float* __restrict__ wn1,
                         const float* __restrict__ b1, unsigned short* __restrict__ h1) {
  int v = blockIdx.x * 4 + (threadIdx.x >> 6);  // one wave per node
  int l = threadIdx.x & 63;
  if (v >= N) return;
  unsigned c = cnt[v];
  unsigned start = roff[v] - c;
  float4 acc = make_float4(0.f, 0.f, 0.f, 0.f);
  for (unsigned e = l; e < c; e += 64) {
    int s = csr[start + e];
    float4 f = *reinterpret_cast<const float4*>(feats + 4 * s);
    acc.x += f.x; acc.y += f.y; acc.z += f.z; acc.w += f.w;
  }
#pragma unroll
  for (int off = 32; off > 0; off >>= 1) {
    acc.x += __shfl_xor(acc.x, off);
    acc.y += __shfl_xor(acc.y, off);
    acc.z += __shfl_xor(acc.z, off);
    acc.w += __shfl_xor(acc.w, off);
  }
  float inv = 1.0f / fmaxf((float)c, 1.0f);
  float m0 = acc.x * inv, m1 = acc.y * inv, m2 = acc.z * inv, m3 = acc.w * inv;
  float4 fv = *reinterpret_cast<const float4*>(feats + 4 * v);
  unsigned pack = 0;
#pragma unroll
  for (int jj = 0; jj < 2; ++jj) {
    int j = 2 * l + jj;
    float o = b1[j];
    o += fv.x * ws1[j] + fv.y * ws1[128 + j] + fv.z * ws1[256 + j] + fv.w * ws1[384 + j];
    o += m0 * wn1[j] + m1 * wn1[128 + j] + m2 * wn1[256 + j] + m3 * wn1[384 + j];
    o = fmaxf(o, 0.f);
    pack |= ((unsigned)f2bf(o)) << (16 * jj);
  }
  *reinterpret_cast<unsigned*>(h1 + v * HID + 2 * l) = pack;
}

// ---------- 128-dim mean aggregation: one wave per node, no atomics ----------
__global__ void k_agg(const unsigned* __restrict__ cnt, const unsigned* __restrict__ roff,
                      const int* __restrict__ csr, const unsigned short* __restrict__ h1,
                      unsigned short* __restrict__ mean) {
  int v = blockIdx.x * 4 + (threadIdx.x >> 6);
  int l = threadIdx.x & 63;
  if (v >= N) return;
  unsigned c = cnt[v];
  unsigned start = roff[v] - c;
  float a0 = 0.f, a1 = 0.f;
  int s = (c > 0) ? csr[start] : 0;
  for (unsigned e = 0; e < c; ++e) {
    unsigned en = e + 1 < c ? e + 1 : c - 1;  // prefetch next csr index
    int snext = csr[start + en];
    unsigned pk = *reinterpret_cast<const unsigned*>(h1 + (size_t)s * HID + 2 * l);
    a0 += bf2f((unsigned short)(pk & 0xffffu));
    a1 += bf2f((unsigned short)(pk >> 16));
    s = snext;
  }
  float inv = 1.0f / fmaxf((float)c, 1.0f);
  unsigned pack = (unsigned)f2bf(a0 * inv) | (((unsigned)f2bf(a1 * inv)) << 16);
  *reinterpret_cast<unsigned*>(mean + (size_t)v * HID + 2 * l) = pack;
}

// ---------- Layer 2 + output head, fused. 64-node tile, 256 threads. ----------
__global__ __launch_bounds__(256, 2) void k_layer2_out(
    const unsigned short* __restrict__ h1, const unsigned short* __restrict__ mean,
    const float* __restrict__ ws2, const float* __restrict__ wn2,
    const float* __restrict__ b2, const float* __restrict__ wout,
    const float* __restrict__ bout, float* __restrict__ out) {
  __shared__ float Ah[64 * 132];
  __shared__ float Am[64 * 132];
  const int t = threadIdx.x;
  const int vbase = blockIdx.x * 64;

  // Stage: 2048 x (4 bf16) per matrix, 8 per thread.
#pragma unroll
  for (int i = 0; i < 8; ++i) {
    int f = t + 256 * i;  // 0..2047
    int v = f >> 5;       // 0..63
    int k4 = f & 31;      // group of 4 along k
    int vg = vbase + v;
    float4 hv = make_float4(0.f, 0.f, 0.f, 0.f);
    float4 av = hv;
    if (vg < N) {
      ushort4 hu = *reinterpret_cast<const ushort4*>(h1 + (size_t)vg * 128 + 4 * k4);
      ushort4 au = *reinterpret_cast<const ushort4*>(mean + (size_t)vg * 128 + 4 * k4);
      hv = make_float4(bf2f(hu.x), bf2f(hu.y), bf2f(hu.z), bf2f(hu.w));
      av = make_float4(bf2f(au.x), bf2f(au.y), bf2f(au.z), bf2f(au.w));
    }
    *reinterpret_cast<float4*>(&Ah[v * 132 + 4 * k4]) = hv;
    *reinterpret_cast<float4*>(&Am[v * 132 + 4 * k4]) = av;
  }
  __syncthreads();

  const int r = t >> 5;  // 0..7 -> nodes 8r..8r+7
  const int c = t & 31;  // cols 4c..4c+3
  float acc[8][4];
#pragma unroll
  for (int i = 0; i < 8; ++i)
#pragma unroll
    for (int jj = 0; jj < 4; ++jj) acc[i][jj] = 0.f;

#pragma unroll 2
  for (int k = 0; k < 128; ++k) {
    float as[8], am[8];
#pragma unroll
    for (int i = 0; i < 8; ++i) {
      as[i] = Ah[(8 * r + i) * 132 + k];
      am[i] = Am[(8 * r + i) * 132 + k];
    }
    float4 wsv = *reinterpret_cast<const float4*>(ws2 + k * 128 + 4 * c);
    float4 wnv = *reinterpret_cast<const float4*>(wn2 + k * 128 + 4 * c);
    float wsa[4] = {wsv.x, wsv.y, wsv.z, wsv.w};
    float wna[4] = {wnv.x, wnv.y, wnv.z, wnv.w};
#pragma unroll
    for (int i = 0; i < 8; ++i)
#pragma unroll
      for (int jj = 0; jj < 4; ++jj)
        acc[i][jj] += as[i] * wsa[jj] + am[i] * wna[jj];
  }
  __syncthreads();

  // h2 = relu(acc + b2) into LDS (reuse Ah), then 128->2 head.
#pragma unroll
  for (int i = 0; i < 8; ++i) {
    int v = 8 * r + i;
#pragma unroll
    for (int jj = 0; jj < 4; ++jj) {
      int j = 4 * c + jj;
      Ah[v * 132 + j] = fmaxf(acc[i][jj] + b2[j], 0.f);
    }
  }
  __syncthreads();

  if (t < 128) {
    int v = t >> 1, cls = t & 1;
    int vg = vbase + v;
    if (vg < N) {
      float sacc = bout[cls];
#pragma unroll 8
      for (int j = 0; j < 128; ++j) sacc += Ah[v * 132 + j] * wout[2 * j + cls];
      out[2 * vg + cls] = sacc;
    }
  }
}

extern "C" void kernel_launch(void* const* d_in, const int* in_sizes, int n_in,
                              void* d_out, int out_size, void* d_ws, size_t ws_size,
                              hipStream_t stream) {
  const float* feats = (const float*)d_in[0];
  const int* src = (const int*)d_in[1];
  const int* dst = (const int*)d_in[2];
  const float* ws1 = (const float*)d_in[3];
  const float* wn1 = (const float*)d_in[4];
  const float* b1 = (const float*)d_in[5];
  const float* ws2 = (const float*)d_in[6];
  const float* wn2 = (const float*)d_in[7];
  const float* b2 = (const float*)d_in[8];
  const float* wout = (const float*)d_in[9];
  const float* bout = (const float*)d_in[10];
  float* out = (float*)d_out;
  const int E = in_sizes[1];

  // Workspace layout (bytes, all 16B-aligned):
  char* p = (char*)d_ws;
  unsigned* cnt = (unsigned*)p;            p += (size_t)N * 4;        // 400000
  unsigned* roff = (unsigned*)p;           p += (size_t)N * 4;        // 400000
  unsigned* bs = (unsigned*)p;             p += 512 * 4;
  unsigned* bsoff = (unsigned*)p;          p += 512 * 4;
  int* csr = (int*)p;                      p += (size_t)E * 4;        // 6.4MB
  unsigned short* h1 = (unsigned short*)p; p += (size_t)N * HID * 2;  // 25.6MB
  unsigned short* mean = (unsigned short*)p;                          // 25.6MB

  hipMemsetAsync(cnt, 0, (size_t)N * 4, stream);

  int egrid = (E + 255) / 256;
  k_count<<<egrid, 256, 0, stream>>>(dst, cnt, E);
  k_blocksum<<<NB, 256, 0, stream>>>(cnt, bs);
  k_scanbs<<<1, 512, 0, stream>>>(bs, bsoff);
  k_scatter_off<<<NB, 256, 0, stream>>>(cnt, bsoff, roff);
  k_fill<<<egrid, 256, 0, stream>>>(src, dst, roff, csr, E);
  k_layer1<<<N / 4, 256, 0, stream>>>(feats, cnt, roff, csr, ws1, wn1, b1, h1);
  k_agg<<<N / 4, 256, 0, stream>>>(cnt, roff, csr, h1, mean);
  k_layer2_out<<<(N + 63) / 64, 256, 0, stream>>>(h1, mean, ws2, wn2, b2, wout, bout, out);
}

// Round 3
// 456.317 us; speedup vs baseline: 4.0821x; 1.1569x over previous
//
#include <hip/hip_runtime.h>
#include <hip/hip_bf16.h>

static constexpr int N = 100000;
static constexpr int HID = 128;
static constexpr int NB = (N + 255) / 256;  // 391 scan blocks

// ---------- bf16 helpers (RNE) ----------
static __device__ __forceinline__ unsigned short f2bf(float x) {
  unsigned u = __float_as_uint(x);
  return (unsigned short)((u + 0x7fffu + ((u >> 16) & 1u)) >> 16);
}
static __device__ __forceinline__ float bf2f(unsigned short u) {
  return __uint_as_float(((unsigned)u) << 16);
}

// ---------- CSR build ----------
__global__ void k_count(const int* __restrict__ dst, unsigned* __restrict__ cnt, int E) {
  int e = blockIdx.x * 256 + threadIdx.x;
  if (e < E) atomicAdd(&cnt[dst[e]], 1u);
}

__global__ void k_blocksum(const unsigned* __restrict__ cnt, unsigned* __restrict__ bs) {
  __shared__ unsigned s[256];
  int i = blockIdx.x * 256 + threadIdx.x;
  s[threadIdx.x] = (i < N) ? cnt[i] : 0u;
  __syncthreads();
  for (int off = 128; off > 0; off >>= 1) {
    if (threadIdx.x < off) s[threadIdx.x] += s[threadIdx.x + off];
    __syncthreads();
  }
  if (threadIdx.x == 0) bs[blockIdx.x] = s[0];
}

__global__ void k_scanbs(const unsigned* __restrict__ bs, unsigned* __restrict__ bsoff) {
  __shared__ unsigned s[512];
  int t = threadIdx.x;
  unsigned v = (t < NB) ? bs[t] : 0u;
  s[t] = v;
  __syncthreads();
  for (int off = 1; off < 512; off <<= 1) {
    unsigned x = (t >= off) ? s[t - off] : 0u;
    __syncthreads();
    s[t] += x;
    __syncthreads();
  }
  if (t < NB) bsoff[t] = s[t] - v;  // exclusive
}

__global__ void k_scatter_off(const unsigned* __restrict__ cnt, const unsigned* __restrict__ bsoff,
                              unsigned* __restrict__ roff) {
  __shared__ unsigned s[256];
  int t = threadIdx.x;
  int i = blockIdx.x * 256 + t;
  unsigned v = (i < N) ? cnt[i] : 0u;
  s[t] = v;
  __syncthreads();
  for (int off = 1; off < 256; off <<= 1) {
    unsigned x = (t >= off) ? s[t - off] : 0u;
    __syncthreads();
    s[t] += x;
    __syncthreads();
  }
  if (i < N) roff[i] = bsoff[blockIdx.x] + s[t] - v;  // exclusive prefix
}

// After this, roff[v] becomes the INCLUSIVE end of row v; start = roff[v]-cnt[v].
__global__ void k_fill(const int* __restrict__ src, const int* __restrict__ dst,
                       unsigned* __restrict__ roff, int* __restrict__ csr, int E) {
  int e = blockIdx.x * 256 + threadIdx.x;
  if (e >= E) return;
  unsigned pos = atomicAdd(&roff[dst[e]], 1u);
  csr[pos] = src[e];
}

// ---------- Layer 1 fused: gather feats + mean + dense(4->128) + relu -> h1 (bf16) ----------
__global__ void k_layer1(const float* __restrict__ feats, const unsigned* __restrict__ cnt,
                         const unsigned* __restrict__ roff, const int* __restrict__ csr,
                         const float* __restrict__ ws1, const float* __restrict__ wn1,
                         const float* __restrict__ b1, unsigned short* __restrict__ h1) {
  int v = blockIdx.x * 4 + (threadIdx.x >> 6);  // one wave per node
  int l = threadIdx.x & 63;
  if (v >= N) return;
  unsigned c = cnt[v];
  unsigned start = roff[v] - c;
  float4 acc = make_float4(0.f, 0.f, 0.f, 0.f);
  for (unsigned e = l; e < c; e += 64) {
    int s = csr[start + e];
    float4 f = *reinterpret_cast<const float4*>(feats + 4 * s);
    acc.x += f.x; acc.y += f.y; acc.z += f.z; acc.w += f.w;
  }
#pragma unroll
  for (int off = 32; off > 0; off >>= 1) {
    acc.x += __shfl_xor(acc.x, off);
    acc.y += __shfl_xor(acc.y, off);
    acc.z += __shfl_xor(acc.z, off);
    acc.w += __shfl_xor(acc.w, off);
  }
  float inv = 1.0f / fmaxf((float)c, 1.0f);
  float m0 = acc.x * inv, m1 = acc.y * inv, m2 = acc.z * inv, m3 = acc.w * inv;
  float4 fv = *reinterpret_cast<const float4*>(feats + 4 * v);
  unsigned pack = 0;
#pragma unroll
  for (int jj = 0; jj < 2; ++jj) {
    int j = 2 * l + jj;
    float o = b1[j];
    o += fv.x * ws1[j] + fv.y * ws1[128 + j] + fv.z * ws1[256 + j] + fv.w * ws1[384 + j];
    o += m0 * wn1[j] + m1 * wn1[128 + j] + m2 * wn1[256 + j] + m3 * wn1[384 + j];
    o = fmaxf(o, 0.f);
    pack |= ((unsigned)f2bf(o)) << (16 * jj);
  }
  *reinterpret_cast<unsigned*>(h1 + v * HID + 2 * l) = pack;
}

// ---------- 128-dim mean aggregation: one wave per node, 4-deep MLP, no atomics ----------
__global__ void k_agg(const unsigned* __restrict__ cnt, const unsigned* __restrict__ roff,
                      const int* __restrict__ csr, const unsigned short* __restrict__ h1,
                      unsigned short* __restrict__ mean) {
  int v = blockIdx.x * 4 + (threadIdx.x >> 6);
  int l = threadIdx.x & 63;
  if (v >= N) return;
  unsigned c = cnt[v];
  unsigned start = roff[v] - c;
  // Two accumulator pairs to shorten the FMA dep chain; merged at the end.
  float x0 = 0.f, x1 = 0.f, y0 = 0.f, y1 = 0.f;
  unsigned e = 0;
  // 4 independent row-gathers in flight per iteration.
  for (; e + 4 <= c; e += 4) {
    int s0 = csr[start + e + 0];
    int s1 = csr[start + e + 1];
    int s2 = csr[start + e + 2];
    int s3 = csr[start + e + 3];
    unsigned p0 = *reinterpret_cast<const unsigned*>(h1 + (size_t)s0 * HID + 2 * l);
    unsigned p1 = *reinterpret_cast<const unsigned*>(h1 + (size_t)s1 * HID + 2 * l);
    unsigned p2 = *reinterpret_cast<const unsigned*>(h1 + (size_t)s2 * HID + 2 * l);
    unsigned p3 = *reinterpret_cast<const unsigned*>(h1 + (size_t)s3 * HID + 2 * l);
    x0 += bf2f((unsigned short)(p0 & 0xffffu)) + bf2f((unsigned short)(p1 & 0xffffu));
    x1 += bf2f((unsigned short)(p0 >> 16)) + bf2f((unsigned short)(p1 >> 16));
    y0 += bf2f((unsigned short)(p2 & 0xffffu)) + bf2f((unsigned short)(p3 & 0xffffu));
    y1 += bf2f((unsigned short)(p2 >> 16)) + bf2f((unsigned short)(p3 >> 16));
  }
  for (; e < c; ++e) {
    int s = csr[start + e];
    unsigned pk = *reinterpret_cast<const unsigned*>(h1 + (size_t)s * HID + 2 * l);
    x0 += bf2f((unsigned short)(pk & 0xffffu));
    x1 += bf2f((unsigned short)(pk >> 16));
  }
  float a0 = x0 + y0, a1 = x1 + y1;
  float inv = 1.0f / fmaxf((float)c, 1.0f);
  unsigned pack = (unsigned)f2bf(a0 * inv) | (((unsigned)f2bf(a1 * inv)) << 16);
  *reinterpret_cast<unsigned*>(mean + (size_t)v * HID + 2 * l) = pack;
}

// ---------- Layer 2 + output head, fused. 64-node tile, 256 threads. ----------
__global__ __launch_bounds__(256, 2) void k_layer2_out(
    const unsigned short* __restrict__ h1, const unsigned short* __restrict__ mean,
    const float* __restrict__ ws2, const float* __restrict__ wn2,
    const float* __restrict__ b2, const float* __restrict__ wout,
    const float* __restrict__ bout, float* __restrict__ out) {
  __shared__ float Ah[64 * 132];
  __shared__ float Am[64 * 132];
  const int t = threadIdx.x;
  const int vbase = blockIdx.x * 64;

  // Stage: 2048 x (4 bf16) per matrix, 8 per thread.
#pragma unroll
  for (int i = 0; i < 8; ++i) {
    int f = t + 256 * i;  // 0..2047
    int v = f >> 5;       // 0..63
    int k4 = f & 31;      // group of 4 along k
    int vg = vbase + v;
    float4 hv = make_float4(0.f, 0.f, 0.f, 0.f);
    float4 av = hv;
    if (vg < N) {
      ushort4 hu = *reinterpret_cast<const ushort4*>(h1 + (size_t)vg * 128 + 4 * k4);
      ushort4 au = *reinterpret_cast<const ushort4*>(mean + (size_t)vg * 128 + 4 * k4);
      hv = make_float4(bf2f(hu.x), bf2f(hu.y), bf2f(hu.z), bf2f(hu.w));
      av = make_float4(bf2f(au.x), bf2f(au.y), bf2f(au.z), bf2f(au.w));
    }
    *reinterpret_cast<float4*>(&Ah[v * 132 + 4 * k4]) = hv;
    *reinterpret_cast<float4*>(&Am[v * 132 + 4 * k4]) = av;
  }
  __syncthreads();

  const int r = t >> 5;  // 0..7 -> nodes 8r..8r+7
  const int c = t & 31;  // cols 4c..4c+3
  float acc[8][4];
#pragma unroll
  for (int i = 0; i < 8; ++i)
#pragma unroll
    for (int jj = 0; jj < 4; ++jj) acc[i][jj] = 0.f;

#pragma unroll 2
  for (int k = 0; k < 128; ++k) {
    float as[8], am[8];
#pragma unroll
    for (int i = 0; i < 8; ++i) {
      as[i] = Ah[(8 * r + i) * 132 + k];
      am[i] = Am[(8 * r + i) * 132 + k];
    }
    float4 wsv = *reinterpret_cast<const float4*>(ws2 + k * 128 + 4 * c);
    float4 wnv = *reinterpret_cast<const float4*>(wn2 + k * 128 + 4 * c);
    float wsa[4] = {wsv.x, wsv.y, wsv.z, wsv.w};
    float wna[4] = {wnv.x, wnv.y, wnv.z, wnv.w};
#pragma unroll
    for (int i = 0; i < 8; ++i)
#pragma unroll
      for (int jj = 0; jj < 4; ++jj)
        acc[i][jj] += as[i] * wsa[jj] + am[i] * wna[jj];
  }
  __syncthreads();

  // h2 = relu(acc + b2) into LDS (reuse Ah), then 128->2 head.
#pragma unroll
  for (int i = 0; i < 8; ++i) {
    int v = 8 * r + i;
#pragma unroll
    for (int jj = 0; jj < 4; ++jj) {
      int j = 4 * c + jj;
      Ah[v * 132 + j] = fmaxf(acc[i][jj] + b2[j], 0.f);
    }
  }
  __syncthreads();

  if (t < 128) {
    int v = t >> 1, cls = t & 1;
    int vg = vbase + v;
    if (vg < N) {
      float sacc = bout[cls];
#pragma unroll 8
      for (int j = 0; j < 128; ++j) sacc += Ah[v * 132 + j] * wout[2 * j + cls];
      out[2 * vg + cls] = sacc;
    }
  }
}

extern "C" void kernel_launch(void* const* d_in, const int* in_sizes, int n_in,
                              void* d_out, int out_size, void* d_ws, size_t ws_size,
                              hipStream_t stream) {
  const float* feats = (const float*)d_in[0];
  const int* src = (const int*)d_in[1];
  const int* dst = (const int*)d_in[2];
  const float* ws1 = (const float*)d_in[3];
  const float* wn1 = (const float*)d_in[4];
  const float* b1 = (const float*)d_in[5];
  const float* ws2 = (const float*)d_in[6];
  const float* wn2 = (const float*)d_in[7];
  const float* b2 = (const float*)d_in[8];
  const float* wout = (const float*)d_in[9];
  const float* bout = (const float*)d_in[10];
  float* out = (float*)d_out;
  const int E = in_sizes[1];

  // Workspace layout (bytes, all 16B-aligned):
  char* p = (char*)d_ws;
  unsigned* cnt = (unsigned*)p;            p += (size_t)N * 4;        // 400000
  unsigned* roff = (unsigned*)p;           p += (size_t)N * 4;        // 400000
  unsigned* bs = (unsigned*)p;             p += 512 * 4;
  unsigned* bsoff = (unsigned*)p;          p += 512 * 4;
  int* csr = (int*)p;                      p += (size_t)E * 4;        // 6.4MB
  unsigned short* h1 = (unsigned short*)p; p += (size_t)N * HID * 2;  // 25.6MB
  unsigned short* mean = (unsigned short*)p;                          // 25.6MB

  hipMemsetAsync(cnt, 0, (size_t)N * 4, stream);

  int egrid = (E + 255) / 256;
  k_count<<<egrid, 256, 0, stream>>>(dst, cnt, E);
  k_blocksum<<<NB, 256, 0, stream>>>(cnt, bs);
  k_scanbs<<<1, 512, 0, stream>>>(bs, bsoff);
  k_scatter_off<<<NB, 256, 0, stream>>>(cnt, bsoff, roff);
  k_fill<<<egrid, 256, 0, stream>>>(src, dst, roff, csr, E);
  k_layer1<<<N / 4, 256, 0, stream>>>(feats, cnt, roff, csr, ws1, wn1, b1, h1);
  k_agg<<<N / 4, 256, 0, stream>>>(cnt, roff, csr, h1, mean);
  k_layer2_out<<<(N + 63) / 64, 256, 0, stream>>>(h1, mean, ws2, wn2, b2, wout, bout, out);
}

// Round 4
// 322.494 us; speedup vs baseline: 5.7761x; 1.4150x over previous
//
#include <hip/hip_runtime.h>
#include <hip/hip_bf16.h>

static constexpr int N = 100000;
static constexpr int HID = 128;
static constexpr int NB = (N + 255) / 256;  // 391 scan blocks

typedef short v8s __attribute__((ext_vector_type(8)));
typedef float v4f __attribute__((ext_vector_type(4)));
typedef unsigned short u16x8 __attribute__((ext_vector_type(8)));

// ---------- bf16 helpers (RNE) ----------
static __device__ __forceinline__ unsigned short f2bf(float x) {
  unsigned u = __float_as_uint(x);
  return (unsigned short)((u + 0x7fffu + ((u >> 16) & 1u)) >> 16);
}
static __device__ __forceinline__ float bf2f(unsigned short u) {
  return __uint_as_float(((unsigned)u) << 16);
}

// ---------- CSR build (XCD-partitioned by dst range to keep scatter L2-local) ----------
__global__ void k_count(const int* __restrict__ dst, unsigned* __restrict__ cnt, int E) {
  int xcd = blockIdx.x & 7;
  int chunk = blockIdx.x >> 3;
  int lo = xcd * 12500, hi = lo + 12500;  // N/8 = 12500 exactly
  int e0 = chunk * 4096;
  int e1 = min(e0 + 4096, E);
  for (int e = e0 + threadIdx.x; e < e1; e += 256) {
    int d = dst[e];
    if (d >= lo && d < hi) atomicAdd(&cnt[d], 1u);
  }
}

__global__ void k_blocksum(const unsigned* __restrict__ cnt, unsigned* __restrict__ bs) {
  __shared__ unsigned s[256];
  int i = blockIdx.x * 256 + threadIdx.x;
  s[threadIdx.x] = (i < N) ? cnt[i] : 0u;
  __syncthreads();
  for (int off = 128; off > 0; off >>= 1) {
    if (threadIdx.x < off) s[threadIdx.x] += s[threadIdx.x + off];
    __syncthreads();
  }
  if (threadIdx.x == 0) bs[blockIdx.x] = s[0];
}

__global__ void k_scanbs(const unsigned* __restrict__ bs, unsigned* __restrict__ bsoff) {
  __shared__ unsigned s[512];
  int t = threadIdx.x;
  unsigned v = (t < NB) ? bs[t] : 0u;
  s[t] = v;
  __syncthreads();
  for (int off = 1; off < 512; off <<= 1) {
    unsigned x = (t >= off) ? s[t - off] : 0u;
    __syncthreads();
    s[t] += x;
    __syncthreads();
  }
  if (t < NB) bsoff[t] = s[t] - v;  // exclusive
}

__global__ void k_scatter_off(const unsigned* __restrict__ cnt, const unsigned* __restrict__ bsoff,
                              unsigned* __restrict__ roff) {
  __shared__ unsigned s[256];
  int t = threadIdx.x;
  int i = blockIdx.x * 256 + t;
  unsigned v = (i < N) ? cnt[i] : 0u;
  s[t] = v;
  __syncthreads();
  for (int off = 1; off < 256; off <<= 1) {
    unsigned x = (t >= off) ? s[t - off] : 0u;
    __syncthreads();
    s[t] += x;
    __syncthreads();
  }
  if (i < N) roff[i] = bsoff[blockIdx.x] + s[t] - v;  // exclusive prefix
}

// After this, roff[v] becomes the INCLUSIVE end of row v; start = roff[v]-cnt[v].
__global__ void k_fill(const int* __restrict__ src, const int* __restrict__ dst,
                       unsigned* __restrict__ roff, int* __restrict__ csr, int E) {
  int xcd = blockIdx.x & 7;
  int chunk = blockIdx.x >> 3;
  int lo = xcd * 12500, hi = lo + 12500;
  int e0 = chunk * 4096;
  int e1 = min(e0 + 4096, E);
  for (int e = e0 + threadIdx.x; e < e1; e += 256) {
    int d = dst[e];
    if (d >= lo && d < hi) {
      unsigned pos = atomicAdd(&roff[d], 1u);
      csr[pos] = src[e];
    }
  }
}

// ---------- Layer 1 fused: gather feats + mean + dense(4->128) + relu -> h1 (bf16) ----------
__global__ void k_layer1(const float* __restrict__ feats, const unsigned* __restrict__ cnt,
                         const unsigned* __restrict__ roff, const int* __restrict__ csr,
                         const float* __restrict__ ws1, const float* __restrict__ wn1,
                         const float* __restrict__ b1, unsigned short* __restrict__ h1) {
  int v = blockIdx.x * 4 + (threadIdx.x >> 6);  // one wave per node
  int l = threadIdx.x & 63;
  if (v >= N) return;
  unsigned c = cnt[v];
  unsigned start = roff[v] - c;
  float4 acc = make_float4(0.f, 0.f, 0.f, 0.f);
  for (unsigned e = l; e < c; e += 64) {
    int s = csr[start + e];
    float4 f = *reinterpret_cast<const float4*>(feats + 4 * s);
    acc.x += f.x; acc.y += f.y; acc.z += f.z; acc.w += f.w;
  }
#pragma unroll
  for (int off = 32; off > 0; off >>= 1) {
    acc.x += __shfl_xor(acc.x, off);
    acc.y += __shfl_xor(acc.y, off);
    acc.z += __shfl_xor(acc.z, off);
    acc.w += __shfl_xor(acc.w, off);
  }
  float inv = 1.0f / fmaxf((float)c, 1.0f);
  float m0 = acc.x * inv, m1 = acc.y * inv, m2 = acc.z * inv, m3 = acc.w * inv;
  float4 fv = *reinterpret_cast<const float4*>(feats + 4 * v);
  unsigned pack = 0;
#pragma unroll
  for (int jj = 0; jj < 2; ++jj) {
    int j = 2 * l + jj;
    float o = b1[j];
    o += fv.x * ws1[j] + fv.y * ws1[128 + j] + fv.z * ws1[256 + j] + fv.w * ws1[384 + j];
    o += m0 * wn1[j] + m1 * wn1[128 + j] + m2 * wn1[256 + j] + m3 * wn1[384 + j];
    o = fmaxf(o, 0.f);
    pack |= ((unsigned)f2bf(o)) << (16 * jj);
  }
  *reinterpret_cast<unsigned*>(h1 + v * HID + 2 * l) = pack;
}

// ---------- 128-dim mean aggregation: one wave per node, 4-deep MLP, no atomics ----------
__global__ void k_agg(const unsigned* __restrict__ cnt, const unsigned* __restrict__ roff,
                      const int* __restrict__ csr, const unsigned short* __restrict__ h1,
                      unsigned short* __restrict__ mean) {
  int v = blockIdx.x * 4 + (threadIdx.x >> 6);
  int l = threadIdx.x & 63;
  if (v >= N) return;
  unsigned c = cnt[v];
  unsigned start = roff[v] - c;
  float x0 = 0.f, x1 = 0.f, y0 = 0.f, y1 = 0.f;
  unsigned e = 0;
  for (; e + 4 <= c; e += 4) {
    int s0 = csr[start + e + 0];
    int s1 = csr[start + e + 1];
    int s2 = csr[start + e + 2];
    int s3 = csr[start + e + 3];
    unsigned p0 = *reinterpret_cast<const unsigned*>(h1 + (size_t)s0 * HID + 2 * l);
    unsigned p1 = *reinterpret_cast<const unsigned*>(h1 + (size_t)s1 * HID + 2 * l);
    unsigned p2 = *reinterpret_cast<const unsigned*>(h1 + (size_t)s2 * HID + 2 * l);
    unsigned p3 = *reinterpret_cast<const unsigned*>(h1 + (size_t)s3 * HID + 2 * l);
    x0 += bf2f((unsigned short)(p0 & 0xffffu)) + bf2f((unsigned short)(p1 & 0xffffu));
    x1 += bf2f((unsigned short)(p0 >> 16)) + bf2f((unsigned short)(p1 >> 16));
    y0 += bf2f((unsigned short)(p2 & 0xffffu)) + bf2f((unsigned short)(p3 & 0xffffu));
    y1 += bf2f((unsigned short)(p2 >> 16)) + bf2f((unsigned short)(p3 >> 16));
  }
  for (; e < c; ++e) {
    int s = csr[start + e];
    unsigned pk = *reinterpret_cast<const unsigned*>(h1 + (size_t)s * HID + 2 * l);
    x0 += bf2f((unsigned short)(pk & 0xffffu));
    x1 += bf2f((unsigned short)(pk >> 16));
  }
  float a0 = x0 + y0, a1 = x1 + y1;
  float inv = 1.0f / fmaxf((float)c, 1.0f);
  unsigned pack = (unsigned)f2bf(a0 * inv) | (((unsigned)f2bf(a1 * inv)) << 16);
  *reinterpret_cast<unsigned*>(mean + (size_t)v * HID + 2 * l) = pack;
}

// ---------- One-time weight prep: split-bf16, MFMA-fragment-ordered ----------
// Frag f = (ks*4 + m)*8 + cf, m in {0:Ws_hi, 1:Wn_hi, 2:Ws_lo, 3:Wn_lo}.
// wp[f*512 + lane*8 + i] = W[ks*32 + (lane>>4)*8 + i][cf*16 + (lane&15)]
__global__ void k_wprep(const float* __restrict__ ws2, const float* __restrict__ wn2,
                        unsigned short* __restrict__ wp) {
  int b = blockIdx.x;     // 64 blocks: mat(2) x ks(4) x cf(8)
  int mat = b >> 5;       // 0: ws2, 1: wn2
  int ks = (b >> 3) & 3;
  int cf = b & 7;
  int l = threadIdx.x;    // 64
  const float* W = mat ? wn2 : ws2;
  int col = cf * 16 + (l & 15);
  int k0 = ks * 32 + (l >> 4) * 8;
  u16x8 h8, l8;
#pragma unroll
  for (int i = 0; i < 8; ++i) {
    float w = W[(k0 + i) * 128 + col];
    unsigned short h = f2bf(w);
    h8[i] = h;
    l8[i] = f2bf(w - bf2f(h));
  }
  int fhi = (ks * 4 + mat) * 8 + cf;
  int flo = (ks * 4 + mat + 2) * 8 + cf;
  *reinterpret_cast<u16x8*>(wp + fhi * 512 + l * 8) = h8;
  *reinterpret_cast<u16x8*>(wp + flo * 512 + l * 8) = l8;
}

// ---------- Layer 2 + head via bf16 MFMA (split-bf16 weights). ----------
// 4 waves/block, 64 nodes/wave. acc[rf][cf]: rows rf*16+(l>>4)*4+j, col cf*16+(l&15).
__global__ __launch_bounds__(256) void k_l2_mfma(
    const unsigned short* __restrict__ h1, const unsigned short* __restrict__ mean,
    const unsigned short* __restrict__ wp, const float* __restrict__ b2,
    const float* __restrict__ wout, const float* __restrict__ bout,
    float* __restrict__ out) {
  const int l = threadIdx.x & 63;
  const int wv = threadIdx.x >> 6;
  const size_t vbase = (size_t)blockIdx.x * 256 + (size_t)wv * 64;
  const int rlane = l & 15;
  const int kg = l >> 4;

  v4f acc[4][8];
#pragma unroll
  for (int rf = 0; rf < 4; ++rf)
#pragma unroll
    for (int cf = 0; cf < 8; ++cf) acc[rf][cf] = (v4f)(0.f);

#pragma unroll
  for (int ks = 0; ks < 4; ++ks) {
    v8s ah[4], am[4];
#pragma unroll
    for (int rf = 0; rf < 4; ++rf) {
      size_t row = vbase + rf * 16 + rlane;
      if (row >= N) row = N - 1;  // tail clamp (store is guarded)
      size_t off = row * HID + ks * 32 + kg * 8;
      ah[rf] = *reinterpret_cast<const v8s*>(h1 + off);
      am[rf] = *reinterpret_cast<const v8s*>(mean + off);
    }
#pragma unroll
    for (int m = 0; m < 4; ++m) {  // Ws_hi, Wn_hi, Ws_lo, Wn_lo
#pragma unroll
      for (int cf = 0; cf < 8; ++cf) {
        v8s bf = *reinterpret_cast<const v8s*>(wp + ((ks * 4 + m) * 8 + cf) * 512 + l * 8);
#pragma unroll
        for (int rf = 0; rf < 4; ++rf) {
          acc[rf][cf] = __builtin_amdgcn_mfma_f32_16x16x32_bf16(
              (m & 1) ? am[rf] : ah[rf], bf, acc[rf][cf], 0, 0, 0);
        }
      }
    }
  }

  // Epilogue: h2 = relu(acc + b2), head out = h2 @ wout + bout.
  float b2c[8], w0c[8], w1c[8];
#pragma unroll
  for (int cf = 0; cf < 8; ++cf) {
    int col = cf * 16 + rlane;
    b2c[cf] = b2[col];
    w0c[cf] = wout[col * 2 + 0];
    w1c[cf] = wout[col * 2 + 1];
  }
  const float bo0 = bout[0], bo1 = bout[1];
#pragma unroll
  for (int rf = 0; rf < 4; ++rf) {
#pragma unroll
    for (int j = 0; j < 4; ++j) {
      float s0 = 0.f, s1 = 0.f;
#pragma unroll
      for (int cf = 0; cf < 8; ++cf) {
        float h2 = fmaxf(acc[rf][cf][j] + b2c[cf], 0.f);
        s0 += h2 * w0c[cf];
        s1 += h2 * w1c[cf];
      }
#pragma unroll
      for (int off = 1; off < 16; off <<= 1) {  // reduce over the 16-lane row group
        s0 += __shfl_xor(s0, off);
        s1 += __shfl_xor(s1, off);
      }
      size_t row = vbase + rf * 16 + kg * 4 + j;
      if (row < N) {
        if (rlane == 0) out[row * 2 + 0] = s0 + bo0;
        if (rlane == 1) out[row * 2 + 1] = s1 + bo1;
      }
    }
  }
}

extern "C" void kernel_launch(void* const* d_in, const int* in_sizes, int n_in,
                              void* d_out, int out_size, void* d_ws, size_t ws_size,
                              hipStream_t stream) {
  const float* feats = (const float*)d_in[0];
  const int* src = (const int*)d_in[1];
  const int* dst = (const int*)d_in[2];
  const float* ws1 = (const float*)d_in[3];
  const float* wn1 = (const float*)d_in[4];
  const float* b1 = (const float*)d_in[5];
  const float* ws2 = (const float*)d_in[6];
  const float* wn2 = (const float*)d_in[7];
  const float* b2 = (const float*)d_in[8];
  const float* wout = (const float*)d_in[9];
  const float* bout = (const float*)d_in[10];
  float* out = (float*)d_out;
  const int E = in_sizes[1];

  // Workspace layout (16B-aligned):
  char* p = (char*)d_ws;
  unsigned* cnt = (unsigned*)p;            p += (size_t)N * 4;
  unsigned* roff = (unsigned*)p;           p += (size_t)N * 4;
  unsigned* bs = (unsigned*)p;             p += 512 * 4;
  unsigned* bsoff = (unsigned*)p;          p += 512 * 4;
  int* csr = (int*)p;                      p += (size_t)E * 4;
  unsigned short* h1 = (unsigned short*)p; p += (size_t)N * HID * 2;
  unsigned short* mean = (unsigned short*)p; p += (size_t)N * HID * 2;
  unsigned short* wp = (unsigned short*)p;  // 4*128*128 bf16 = 128KB

  hipMemsetAsync(cnt, 0, (size_t)N * 4, stream);

  int nchunk = (E + 4095) / 4096;
  k_wprep<<<64, 64, 0, stream>>>(ws2, wn2, wp);
  k_count<<<nchunk * 8, 256, 0, stream>>>(dst, cnt, E);
  k_blocksum<<<NB, 256, 0, stream>>>(cnt, bs);
  k_scanbs<<<1, 512, 0, stream>>>(bs, bsoff);
  k_scatter_off<<<NB, 256, 0, stream>>>(cnt, bsoff, roff);
  k_fill<<<nchunk * 8, 256, 0, stream>>>(src, dst, roff, csr, E);
  k_layer1<<<N / 4, 256, 0, stream>>>(feats, cnt, roff, csr, ws1, wn1, b1, h1);
  k_agg<<<N / 4, 256, 0, stream>>>(cnt, roff, csr, h1, mean);
  k_l2_mfma<<<(N + 255) / 256, 256, 0, stream>>>(h1, mean, wp, b2, wout, bout, out);
}